// Round 15
// baseline (856.003 us; speedup 1.0000x reference)
//
#include <hip/hip_runtime.h>
#include <hip/hip_bf16.h>
#include <math.h>

typedef __hip_bfloat16 bf16;
typedef __attribute__((ext_vector_type(8))) short short8v;   // 8 bf16 (4 VGPRs)
typedef __attribute__((ext_vector_type(4))) float float4v;   // mfma acc

#define NODES 20000
#define EDG   400000
#define ETOT  (EDG + NODES)
#define GB    200
#define HEADS 10
#define FD    78
#define HIDD  780
#define SEQL  1000
#define VOCS  26
#define EMBD  128
#define NFC   32
#define KSZ   8
#define COUT  993
#define KFXT  (NFC * COUT)

#define MPAD  20096   // 157*128
#define NPADB 896     // 7*128
#define KP2   800     // K=780 padded to 25*32
#define HP    800     // h2/x2 row stride == KP2; 2 panels x 400 feats
#define PNL   2
#define PF    400     // feats per panel = 50 lanes x 8
#define MB2   208     // padded batch rows (13*16) for fxt / cT
#define FXT_KS 128    // fxt K-split blocks per n-tile
#define HK    96      // per-head K pad (78 -> 96)
#define AGS   960     // aggx row stride = HEADS * HK

// diag[0] bits: 1=CSR structural, 2=gat den NaN, 8=gat acc NaN, 16=gcn acc NaN,
// 4096=conv NaN, 8192=idx OOB
// diag[1]: 0 = inputs are bf16, 1 = inputs are fp32

__device__ __forceinline__ float us2f(unsigned short u) {
  unsigned int i = ((unsigned int)u) << 16; float f; __builtin_memcpy(&f, &i, 4); return f;
}
__device__ __forceinline__ float b2f(bf16 v) { return __bfloat162float(v); }
__device__ __forceinline__ float ldany(const void* p, size_t i, int m) {
  if (m) return ((const float*)p)[i];
  return b2f(((const bf16*)p)[i]);
}
__device__ __forceinline__ bool nanf_(float v) { return v != v; }
__device__ __forceinline__ unsigned short f2us(float v) {
  bf16 b = __float2bfloat16(v); unsigned short u; __builtin_memcpy(&u, &b, 2); return u;
}

// ---------- runtime dtype detection on x
__global__ void k_detect(const void* x, int* diag) {
  int t = threadIdx.x;
  const unsigned short* u = (const unsigned short*)x;
  int hit = 0;
  for (int i = t; i < 4096; i += 256) {
    float v = us2f(u[i]);
    if (nanf_(v) || fabsf(v) > 1e6f) hit = 1;
  }
  if (hit) diag[1] = 1;  // benign race
}

// ---------- LDS-tiled transpose gcn_W [780][780] -> gcnWt[NPADB][KP2]
__global__ __launch_bounds__(256) void k_tr_gcnw(const void* gw, bf16* Wt,
                                                 const int* diag) {
  __shared__ float tile[32][33];
  int k0 = blockIdx.x * 32, n0 = blockIdx.y * 32;
  int mode = diag[1];
  int t = threadIdx.x;
  int tn = t & 31, tk = t >> 5;  // 8 rows per pass
  for (int kk = tk; kk < 32; kk += 8) {
    int gk = k0 + kk, gn = n0 + tn;
    tile[kk][tn] = (gk < HIDD && gn < HIDD) ? ldany(gw, (size_t)gk * HIDD + gn, mode) : 0.f;
  }
  __syncthreads();
  for (int nn = tk; nn < 32; nn += 8) {
    int gn = n0 + nn, gk = k0 + tn;
    if (gn < NPADB && gk < KP2)
      Wt[(size_t)gn * KP2 + gk] = __float2bfloat16(tile[tn][nn]);
  }
}

// ---------- merged GAT prep: fold gat_a (idx<780) + per-head Wt2 (idx<122880)
__global__ void k_prepg(const void* gat_W, const void* a_src, const void* a_dst,
                        float* Ws, float* Wd, bf16* Wt2, const int* diag) {
  int idx = blockIdx.x * 256 + threadIdx.x;
  int mode = diag[1];
  if (idx < FD * HEADS) {
    int k = idx / HEADS, hd = idx % HEADS;
    float s = 0.f, d = 0.f;
    for (int f = 0; f < FD; ++f) {
      float w = ldany(gat_W, (size_t)k * HIDD + hd * FD + f, mode);
      s += w * ldany(a_src, (size_t)hd * FD + f, mode);
      d += w * ldany(a_dst, (size_t)hd * FD + f, mode);
    }
    Ws[idx] = s;
    Wd[idx] = d;
  }
  if (idx < HEADS * 128 * HK) {
    int h = idx / (128 * HK);
    int r = idx % (128 * HK);
    int n = r / HK, k = r % HK;
    float v = (n < FD && k < FD) ? ldany(gat_W, (size_t)k * HIDD + h * FD + n, mode) : 0.f;
    Wt2[idx] = __float2bfloat16(v);
  }
}

// ---------- zero x1p pad rows (>= NODES) and pad cols [780, 800)
__global__ void k_zero_x1pad(bf16* x1p) {
  int i = blockIdx.x * 256 + threadIdx.x;
  int nr = (MPAD - NODES) * KP2;  // 76800
  if (i < nr) {
    x1p[(size_t)NODES * KP2 + i] = __float2bfloat16(0.f);
  } else {
    int j = i - nr;
    if (j < NODES * 20) {
      int d = j / 20, c = HIDD + (j % 20);
      x1p[(size_t)d * KP2 + c] = __float2bfloat16(0.f);
    }
  }
}

// ---------- MFMA bf16 GEMM: C[gm*ldc+gn] = A[M x Kp (lda)] @ Bt[n][k] (ldb)
#define MT 128
#define NT 128
#define BK 32
#define LP 40
__global__ __launch_bounds__(256) void k_gemm_mfma(const bf16* A, int lda,
                                                   const bf16* Bt, int ldb,
                                                   bf16* C, int ldc, int Ncap,
                                                   int M, int Kp) {
  __shared__ __align__(16) bf16 As[MT * LP];
  __shared__ __align__(16) bf16 Bs[NT * LP];
  int t = threadIdx.x;
  int lane = t & 63, w = t >> 6;
  int wr = (w >> 1) * 64, wc = (w & 1) * 64;
  int quad = lane >> 4, mr = lane & 15;
  int m0 = blockIdx.y * MT, n0 = blockIdx.x * NT;
  float4v acc[4][4];
#pragma unroll
  for (int i = 0; i < 4; ++i)
#pragma unroll
    for (int j = 0; j < 4; ++j) acc[i][j] = (float4v){0.f, 0.f, 0.f, 0.f};

  for (int kc = 0; kc < Kp; kc += BK) {
#pragma unroll
    for (int i = 0; i < 4; ++i) {
      int c = t + i * 256;
      int row = c >> 3, col = (c & 7) * 4;
      *(uint2*)&As[row * LP + col] =
          *(const uint2*)&A[(size_t)(m0 + row) * lda + kc + col];
      *(uint2*)&Bs[row * LP + col] =
          *(const uint2*)&Bt[(size_t)(n0 + row) * ldb + kc + col];
    }
    __syncthreads();
    short8v af[4], bfr[4];
#pragma unroll
    for (int i = 0; i < 4; ++i)
      af[i] = *(const short8v*)&As[(wr + i * 16 + mr) * LP + quad * 8];
#pragma unroll
    for (int j = 0; j < 4; ++j)
      bfr[j] = *(const short8v*)&Bs[(wc + j * 16 + mr) * LP + quad * 8];
#pragma unroll
    for (int i = 0; i < 4; ++i)
#pragma unroll
      for (int j = 0; j < 4; ++j)
        acc[i][j] = __builtin_amdgcn_mfma_f32_16x16x32_bf16(af[i], bfr[j], acc[i][j], 0, 0, 0);
    __syncthreads();
  }
#pragma unroll
  for (int i = 0; i < 4; ++i) {
    int gm0 = m0 + wr + i * 16 + quad * 4;
#pragma unroll
    for (int j = 0; j < 4; ++j) {
      int gn = n0 + wc + j * 16 + mr;
      if (gn >= Ncap) continue;
#pragma unroll
      for (int r = 0; r < 4; ++r) {
        int gm = gm0 + r;
        if (gm < M) C[(size_t)gm * ldc + gn] = __float2bfloat16(acc[i][j][r]);
      }
    }
  }
}

// ---------- per-head GAT GEMM: x1[d][h*78+n] = relu(aggx[d][h] @ W_h + b)
__global__ __launch_bounds__(256) void k_hgemm(const bf16* aggx, const bf16* Wt2,
                                               const void* gat_b, bf16* x1,
                                               const int* diag) {
  __shared__ __align__(16) bf16 As[MT * LP];
  __shared__ __align__(16) bf16 Bs[NT * LP];
  int t = threadIdx.x;
  int lane = t & 63, w = t >> 6;
  int wr = (w >> 1) * 64, wc = (w & 1) * 64;
  int quad = lane >> 4, mr = lane & 15;
  int m0 = blockIdx.x * MT, h = blockIdx.y;
  int mode = diag[1];
  const bf16* A = aggx + (size_t)h * HK;
  const bf16* Bt = Wt2 + (size_t)h * 128 * HK;
  float4v acc[4][4];
#pragma unroll
  for (int i = 0; i < 4; ++i)
#pragma unroll
    for (int j = 0; j < 4; ++j) acc[i][j] = (float4v){0.f, 0.f, 0.f, 0.f};

  for (int kc = 0; kc < HK; kc += BK) {
#pragma unroll
    for (int i = 0; i < 4; ++i) {
      int c = t + i * 256;
      int row = c >> 3, col = (c & 7) * 4;
      *(uint2*)&As[row * LP + col] =
          *(const uint2*)&A[(size_t)(m0 + row) * AGS + kc + col];
      *(uint2*)&Bs[row * LP + col] =
          *(const uint2*)&Bt[(size_t)row * HK + kc + col];
    }
    __syncthreads();
    short8v af[4], bfr[4];
#pragma unroll
    for (int i = 0; i < 4; ++i)
      af[i] = *(const short8v*)&As[(wr + i * 16 + mr) * LP + quad * 8];
#pragma unroll
    for (int j = 0; j < 4; ++j)
      bfr[j] = *(const short8v*)&Bs[(wc + j * 16 + mr) * LP + quad * 8];
#pragma unroll
    for (int i = 0; i < 4; ++i)
#pragma unroll
      for (int j = 0; j < 4; ++j)
        acc[i][j] = __builtin_amdgcn_mfma_f32_16x16x32_bf16(af[i], bfr[j], acc[i][j], 0, 0, 0);
    __syncthreads();
  }
#pragma unroll
  for (int i = 0; i < 4; ++i) {
    int gm0 = m0 + wr + i * 16 + quad * 4;
#pragma unroll
    for (int j = 0; j < 4; ++j) {
      int gn = wc + j * 16 + mr;
      if (gn >= FD) continue;
      float bs = ldany(gat_b, h * FD + gn, mode);
#pragma unroll
      for (int r = 0; r < 4; ++r) {
        int gm = gm0 + r;
        if (gm < NODES)
          x1[(size_t)gm * KP2 + h * FD + gn] =
              __float2bfloat16(fmaxf(acc[i][j][r] + bs, 0.f));
      }
    }
  }
}

// ---------- MFMA small-M dense layer (generic; all MLP layers but fxt)
#define MLP_NT 64
#define MLP_BK 32
#define MLP_MT 208
#define MLP_LP 40
__global__ __launch_bounds__(256) void k_mlp_mfma(const void* A, int lda, const void* Bw,
                                                  const void* bias, float* out, int ostride,
                                                  int ooff, int M, int Nn, int K,
                                                  int ksplit, int aRelu, int aBf16,
                                                  const int* diag) {
  __shared__ __align__(16) bf16 As[MLP_MT * MLP_LP];
  __shared__ __align__(16) bf16 Bs[MLP_NT * MLP_LP];
  int mode = diag[1];
  int t = threadIdx.x;
  int lane = t & 63, w = t >> 6;
  int quad = lane >> 4, mr = lane & 15;
  int n0 = blockIdx.x * MLP_NT;
  int kz = blockIdx.y;
  int nchunks = (K + MLP_BK - 1) / MLP_BK;
  int cpk = (nchunks + ksplit - 1) / ksplit;
  int c0 = kz * cpk, c1 = c0 + cpk;
  if (c1 > nchunks) c1 = nchunks;
  float4v acc[13];
#pragma unroll
  for (int i = 0; i < 13; ++i) acc[i] = (float4v){0.f, 0.f, 0.f, 0.f};

  for (int c = c0; c < c1; ++c) {
    int k0 = c * MLP_BK;
    if (aBf16) {
      const bf16* Ab = (const bf16*)A;
      for (int e = t; e < MLP_MT * 4; e += 256) {
        int row = e >> 2, c8 = (e & 3) * 8;
        int gk = k0 + c8;
        if (row < M && gk + 7 < K) {
          *(uint4*)&As[row * MLP_LP + c8] = *(const uint4*)&Ab[(size_t)row * lda + gk];
        } else {
#pragma unroll
          for (int kk = 0; kk < 8; ++kk) {
            float v = (row < M && gk + kk < K) ? b2f(Ab[(size_t)row * lda + gk + kk]) : 0.f;
            As[row * MLP_LP + c8 + kk] = __float2bfloat16(v);
          }
        }
      }
    } else {
      const float* Af = (const float*)A;
      for (int e = t; e < MLP_MT * 8; e += 256) {
        int row = e >> 3, c4 = (e & 7) * 4;
        int gk = k0 + c4;
        float4 v4 = {0.f, 0.f, 0.f, 0.f};
        if (row < M) {
          if (gk + 3 < K) {
            v4 = *(const float4*)&Af[(size_t)row * lda + gk];
          } else {
            v4.x = (gk + 0 < K) ? Af[(size_t)row * lda + gk + 0] : 0.f;
            v4.y = (gk + 1 < K) ? Af[(size_t)row * lda + gk + 1] : 0.f;
            v4.z = (gk + 2 < K) ? Af[(size_t)row * lda + gk + 2] : 0.f;
            v4.w = (gk + 3 < K) ? Af[(size_t)row * lda + gk + 3] : 0.f;
          }
        }
        if (aRelu) {
          v4.x = fmaxf(v4.x, 0.f); v4.y = fmaxf(v4.y, 0.f);
          v4.z = fmaxf(v4.z, 0.f); v4.w = fmaxf(v4.w, 0.f);
        }
        bf16* dst = &As[row * MLP_LP + c4];
        dst[0] = __float2bfloat16(v4.x); dst[1] = __float2bfloat16(v4.y);
        dst[2] = __float2bfloat16(v4.z); dst[3] = __float2bfloat16(v4.w);
      }
    }
    for (int e = t; e < MLP_NT * MLP_BK; e += 256) {
      int k = e >> 6, col = e & 63;
      int gk = k0 + k, gn = n0 + col;
      float v = (gn < Nn && gk < K) ? ldany(Bw, (size_t)gk * Nn + gn, mode) : 0.f;
      Bs[col * MLP_LP + k] = __float2bfloat16(v);
    }
    __syncthreads();
    short8v bf = *(const short8v*)&Bs[(w * 16 + mr) * MLP_LP + quad * 8];
#pragma unroll
    for (int i = 0; i < 13; ++i) {
      short8v af = *(const short8v*)&As[(i * 16 + mr) * MLP_LP + quad * 8];
      acc[i] = __builtin_amdgcn_mfma_f32_16x16x32_bf16(af, bf, acc[i], 0, 0, 0);
    }
    __syncthreads();
  }
  int gn = n0 + w * 16 + mr;
  if (gn >= Nn) return;
  float bs = (kz == 0) ? ldany(bias, gn, mode) : 0.f;
#pragma unroll
  for (int i = 0; i < 13; ++i) {
    int gm0 = i * 16 + quad * 4;
#pragma unroll
    for (int r = 0; r < 4; ++r) {
      int gm = gm0 + r;
      if (gm >= M) break;
      float v = acc[i][r] + bs;
      float* op = &out[(size_t)gm * ostride + ooff + gn];
      if (ksplit == 1) *op = v;
      else atomicAdd(op, v);
    }
  }
}

// ---------- dedicated fxt: partials = cT[K x 208] @ fxt_W[K x 128]
__global__ __launch_bounds__(256) void k_fxt(const bf16* cT, const void* Bw,
                                             float* part, const int* diag) {
  __shared__ __align__(16) bf16 As[MLP_MT * MLP_LP];
  __shared__ __align__(16) bf16 Bs[MLP_NT * MLP_LP];
  int mode = diag[1];
  int t = threadIdx.x;
  int lane = t & 63, w = t >> 6;
  int quad = lane >> 4, mr = lane & 15;
  int n0 = blockIdx.x * MLP_NT;
  int kz = blockIdx.y;
  int nchunks = KFXT / MLP_BK;                 // 993
  int cpk = (nchunks + FXT_KS - 1) / FXT_KS;   // 8
  int c0 = kz * cpk, c1 = c0 + cpk;
  if (c1 > nchunks) c1 = nchunks;
  float4v acc[13];
#pragma unroll
  for (int i = 0; i < 13; ++i) acc[i] = (float4v){0.f, 0.f, 0.f, 0.f};

  for (int c = c0; c < c1; ++c) {
    int k0 = c * MLP_BK;
    for (int e = t; e < 32 * 52; e += 256) {
      int kk = e / 52, bq = e % 52;
      uint2 u = *(const uint2*)&cT[(size_t)(k0 + kk) * MB2 + bq * 4];
      unsigned short* ap = (unsigned short*)As;
      int mb = bq * 4;
      ap[(mb + 0) * MLP_LP + kk] = (unsigned short)(u.x & 0xffffu);
      ap[(mb + 1) * MLP_LP + kk] = (unsigned short)(u.x >> 16);
      ap[(mb + 2) * MLP_LP + kk] = (unsigned short)(u.y & 0xffffu);
      ap[(mb + 3) * MLP_LP + kk] = (unsigned short)(u.y >> 16);
    }
    for (int e = t; e < MLP_NT * MLP_BK; e += 256) {
      int k = e >> 6, col = e & 63;
      float v = ldany(Bw, (size_t)(k0 + k) * 128 + (n0 + col), mode);
      Bs[col * MLP_LP + k] = __float2bfloat16(v);
    }
    __syncthreads();
    short8v bf = *(const short8v*)&Bs[(w * 16 + mr) * MLP_LP + quad * 8];
#pragma unroll
    for (int i = 0; i < 13; ++i) {
      short8v af = *(const short8v*)&As[(i * 16 + mr) * MLP_LP + quad * 8];
      acc[i] = __builtin_amdgcn_mfma_f32_16x16x32_bf16(af, bf, acc[i], 0, 0, 0);
    }
    __syncthreads();
  }
  int gnl = n0 + w * 16 + mr;
#pragma unroll
  for (int i = 0; i < 13; ++i) {
#pragma unroll
    for (int r = 0; r < 4; ++r) {
      int gm = i * 16 + quad * 4 + r;
      part[((size_t)kz * MB2 + gm) * 128 + gnl] = acc[i][r];
    }
  }
}

// ---------- fxt partial reduction + bias -> xc[:, 128:256]
__global__ __launch_bounds__(128) void k_fxt_red(const float* part, const void* bias,
                                                 float* xc, const int* diag) {
  int gm = blockIdx.x, n = threadIdx.x;
  int mode = diag[1];
  float s = 0.f;
  for (int kz = 0; kz < FXT_KS; ++kz)
    s += part[((size_t)kz * MB2 + gm) * 128 + n];
  xc[(size_t)gm * 256 + 128 + n] = s + ldany(bias, n, mode);
}

// ---------- conv LUT
__global__ void k_prep_mtab(const void* emb, const void* cW, float* Mtab, const int* diag) {
  int idx = blockIdx.x * 256 + threadIdx.x;
  if (idx >= NFC * KSZ * VOCS) return;
  int mode = diag[1];
  int o = idx / (KSZ * VOCS);
  int r = idx % (KSZ * VOCS);
  int k = r / VOCS, v = r % VOCS;
  float acc = 0.f;
  for (int i = 0; i < EMBD; ++i)
    acc += ldany(emb, (size_t)v * EMBD + i, mode) * ldany(cW, ((size_t)o * EMBD + i) * KSZ + k, mode);
  Mtab[idx] = acc;
}

// ---------- a_s = x @ Ws, a_d = x @ Wd
__global__ __launch_bounds__(256) void k_asd(const void* x, const float* Ws, const float* Wd,
                                             float* a_s, float* a_d, const int* diag) {
  __shared__ unsigned short xs[256 * FD];
  __shared__ float ws_sh[FD * HEADS], wd_sh[FD * HEADS];
  int mode = diag[1];
  int nb = blockIdx.x * 256, t = threadIdx.x;
  for (int e = t; e < FD * HEADS; e += 256) { ws_sh[e] = Ws[e]; wd_sh[e] = Wd[e]; }
  for (int e = t; e < 256 * FD; e += 256) {
    int r = e / FD, c = e % FD;
    int gn = nb + r;
    float xv = (gn < NODES) ? ldany(x, (size_t)gn * FD + c, mode) : 0.f;
    xs[e] = f2us(xv);
  }
  __syncthreads();
  int n = nb + t;
  if (n >= NODES) return;
  float as[HEADS], ad[HEADS];
#pragma unroll
  for (int hd = 0; hd < HEADS; ++hd) { as[hd] = 0.f; ad[hd] = 0.f; }
  for (int f = 0; f < FD; ++f) {
    float xv = us2f(xs[t * FD + f]);
#pragma unroll
    for (int hd = 0; hd < HEADS; ++hd) {
      as[hd] += xv * ws_sh[f * HEADS + hd];
      ad[hd] += xv * wd_sh[f * HEADS + hd];
    }
  }
#pragma unroll
  for (int hd = 0; hd < HEADS; ++hd) {
    a_s[n * HEADS + hd] = as[hd];
    a_d[n * HEADS + hd] = ad[hd];
  }
}

// ---------- CSR build
__global__ void k_count(const int* ei, int* cnt, int* diag) {
  int e = blockIdx.x * 256 + threadIdx.x;
  if (e >= ETOT) return;
  int d = (e < EDG) ? ei[EDG + e] : (e - EDG);
  if ((unsigned)d >= NODES) { atomicOr(diag, 8192); d = 0; }
  atomicAdd(&cnt[d], 1);
}

// shfl-based block scan
__global__ __launch_bounds__(1024) void k_scan(const int* cnt, int* rowstart) {
  __shared__ int wsum[16];
  __shared__ int carry;
  int t = threadIdx.x;
  int lane = t & 63, wid = t >> 6;
  if (t == 0) carry = 0;
  __syncthreads();
  for (int c = 0; c < (NODES + 1023) / 1024; ++c) {
    int i = c * 1024 + t;
    int orig = (i < NODES) ? cnt[i] : 0;
    int v = orig;
#pragma unroll
    for (int off = 1; off < 64; off <<= 1) {
      int u = __shfl_up(v, off, 64);
      if (lane >= off) v += u;
    }
    if (lane == 63) wsum[wid] = v;
    __syncthreads();
    if (t == 0) {
      int s = carry;
      for (int j = 0; j < 16; ++j) { int tmp = wsum[j]; wsum[j] = s; s += tmp; }
      carry = s;
    }
    __syncthreads();
    if (i < NODES) rowstart[i] = v - orig + wsum[wid];
    __syncthreads();
  }
  if (t == 0) rowstart[NODES] = carry;
}

__global__ void k_scatter(const int* ei, const int* rowstart, int* cur, int* es_src,
                          int* diag) {
  int e = blockIdx.x * 256 + threadIdx.x;
  if (e >= ETOT) return;
  int s, d;
  if (e < EDG) { s = ei[e]; d = ei[EDG + e]; } else { s = e - EDG; d = s; }
  if ((unsigned)d >= NODES) { atomicOr(diag, 8192); d = 0; }
  if ((unsigned)s >= NODES) { atomicOr(diag, 8192); s = 0; }
  int pos = rowstart[d] + atomicAdd(&cur[d], 1);
  if ((unsigned)pos < (unsigned)ETOT) es_src[pos] = s;
  else atomicOr(diag, 1);
}

// ---------- merged: dinv + CSR check + batch segment starts
__global__ void k_graphmeta(const int* cnt, const int* cur, const int* rowst,
                            const int* batch, float* dinv, int* bstart, int* diag) {
  int n = blockIdx.x * 256 + threadIdx.x;
  if (n >= NODES) return;
  int dg = cnt[n];
  dinv[n] = rsqrtf((float)(dg > 0 ? dg : 1));
  if (cur[n] != cnt[n]) atomicOr(diag, 1);
  if (n == 0 && rowst[NODES] != ETOT) atomicOr(diag, 1);
  int bi = batch[n];
  if ((unsigned)bi >= GB) { atomicOr(diag, 8192); bi = GB - 1; }
  int bp;
  if (n == 0) bp = -1;
  else {
    bp = batch[n - 1];
    if ((unsigned)bp >= GB) bp = GB - 1;
  }
  for (int b = bp + 1; b <= bi; ++b) bstart[b] = n;
  if (n == NODES - 1)
    for (int b = bi + 1; b <= GB; ++b) bstart[b] = NODES;
}

// ---------- FUSED GAT softmax + x-space gather
__global__ __launch_bounds__(64) void k_gatx(const int* es_src, const int* rowst,
                                             const float* a_s, const float* a_d,
                                             const void* x, bf16* aggx, int* diag) {
  __shared__ int ssc[64];
  __shared__ float alw[64 * HEADS];
  int d = blockIdx.x, lane = threadIdx.x;
  int mode = diag[1];
  int start = rowst[d], end = rowst[d + 1];
  float ad[HEADS];
#pragma unroll
  for (int j = 0; j < HEADS; ++j) ad[j] = a_d[d * HEADS + j];

  float mx[HEADS];
#pragma unroll
  for (int j = 0; j < HEADS; ++j) mx[j] = -INFINITY;
  for (int base = start; base < end; base += 64) {
    int ce = base + lane;
    if (ce < end) {
      int s = es_src[ce];
      if ((unsigned)s >= NODES) { atomicOr(diag, 1); s = 0; }
#pragma unroll
      for (int j = 0; j < HEADS; ++j) {
        float v = a_s[s * HEADS + j] + ad[j];
        v = v > 0.f ? v : 0.2f * v;
        mx[j] = fmaxf(mx[j], v);
      }
    }
  }
#pragma unroll
  for (int j = 0; j < HEADS; ++j)
    for (int off = 1; off < 64; off <<= 1) mx[j] = fmaxf(mx[j], __shfl_xor(mx[j], off, 64));

  float den[HEADS];
#pragma unroll
  for (int j = 0; j < HEADS; ++j) den[j] = 0.f;
  int f0 = 2 * lane;
  float acc[HEADS][2];
#pragma unroll
  for (int j = 0; j < HEADS; ++j) { acc[j][0] = 0.f; acc[j][1] = 0.f; }
  for (int base = start; base < end; base += 64) {
    int ce = base + lane;
    if (ce < end) {
      int s = es_src[ce];
      if ((unsigned)s >= NODES) s = 0;
      ssc[lane] = s;
#pragma unroll
      for (int j = 0; j < HEADS; ++j) {
        float v = a_s[s * HEADS + j] + ad[j];
        v = v > 0.f ? v : 0.2f * v;
        float ex = expf(v - mx[j]);
        alw[lane * HEADS + j] = ex;
        den[j] += ex;
      }
    }
    __syncthreads();
    int cnt2 = end - base; if (cnt2 > 64) cnt2 = 64;
    if (lane < 39) {
      for (int e = 0; e < cnt2; ++e) {
        int ss = ssc[e];
        float xv0, xv1;
        if (mode) {
          const float* xf = (const float*)x;
          xv0 = xf[(size_t)ss * FD + f0];
          xv1 = xf[(size_t)ss * FD + f0 + 1];
        } else {
          unsigned int u = *(const unsigned int*)((const unsigned short*)x +
                                                  (size_t)ss * FD + f0);
          xv0 = us2f((unsigned short)(u & 0xffffu));
          xv1 = us2f((unsigned short)(u >> 16));
        }
        const float* al = &alw[e * HEADS];
#pragma unroll
        for (int j = 0; j < HEADS; ++j) {
          acc[j][0] += al[j] * xv0;
          acc[j][1] += al[j] * xv1;
        }
      }
    }
    __syncthreads();
  }
#pragma unroll
  for (int j = 0; j < HEADS; ++j)
    for (int off = 1; off < 64; off <<= 1) den[j] += __shfl_xor(den[j], off, 64);
  if (lane == 0 && (nanf_(den[0]) || nanf_(den[HEADS - 1]))) atomicOr(diag, 2);

  if (lane < 48) {
    if (lane < 39 && (nanf_(acc[0][0]) || nanf_(acc[HEADS - 1][1]))) atomicOr(diag, 8);
    size_t rb = (size_t)d * AGS;
#pragma unroll
    for (int h = 0; h < HEADS; ++h) {
      float r = 1.f / den[h];
      unsigned short o0 = (f0 < FD) ? f2us(acc[h][0] * r) : (unsigned short)0;
      unsigned short o1 = (f0 + 1 < FD) ? f2us(acc[h][1] * r) : (unsigned short)0;
      unsigned int pack = (unsigned int)o0 | ((unsigned int)o1 << 16);
      *(unsigned int*)(aggx + rb + h * HK + f0) = pack;
    }
  }
}

// ---------- GCN panel gather -> x2b; PANEL-MAJOR grid (bid = p*NODES + d)
// so concurrently-resident blocks share one feature panel (L2 residency).
__global__ __launch_bounds__(64) void k_gcng(const int* es_src, const int* rowst,
                                             const float* dinv, const bf16* h2,
                                             const void* gcn_b, bf16* x2b, int* diag) {
  __shared__ int ssc[64];
  __shared__ float nw[64];
  int bid = blockIdx.x;
  int p = bid / NODES, d = bid - p * NODES;
  int lane = threadIdx.x;
  int mode = diag[1];
  int start = rowst[d], end = rowst[d + 1];
  float dd = dinv[d];
  int fb = p * PF + lane * 8;
  float acc[8];
#pragma unroll
  for (int k = 0; k < 8; ++k) acc[k] = 0.f;
  for (int base = start; base < end; base += 64) {
    int ce = base + lane;
    if (ce < end) {
      int s = es_src[ce];
      if ((unsigned)s >= NODES) { atomicOr(diag, 1); s = 0; }
      ssc[lane] = s;
      nw[lane] = dinv[s] * dd;
    }
    __syncthreads();
    int cnt2 = end - base; if (cnt2 > 64) cnt2 = 64;
    if (lane < 50) {
      for (int e = 0; e < cnt2; ++e) {
        int ss = ssc[e];
        float nv = nw[e];
        uint4 u = *(const uint4*)(h2 + (size_t)ss * HP + fb);
        unsigned int uw[4] = {u.x, u.y, u.z, u.w};
#pragma unroll
        for (int k = 0; k < 4; ++k) {
          acc[2 * k]     += nv * us2f((unsigned short)(uw[k] & 0xffffu));
          acc[2 * k + 1] += nv * us2f((unsigned short)(uw[k] >> 16));
        }
      }
    }
    __syncthreads();
  }
  if (lane < 50) {
    if (nanf_(acc[0]) || nanf_(acc[7])) atomicOr(diag, 16);
    unsigned short o[8];
#pragma unroll
    for (int k = 0; k < 8; ++k) {
      int f = fb + k;
      float v = 0.f;
      if (f < HIDD) v = fmaxf(acc[k] + ldany(gcn_b, f, mode), 0.f);
      o[k] = f2us(v);
    }
    uint4 pack;
    __builtin_memcpy(&pack, o, 16);
    *(uint4*)(x2b + (size_t)d * HP + fb) = pack;
  }
}

// ---------- segment pool: xg_pool[b][f] = sum_{d in segment} x2b[d][f]
__global__ __launch_bounds__(256) void k_pool(const bf16* x2b, const int* bstart,
                                              float* xg_pool) {
  int b = blockIdx.x, t = threadIdx.x;
  if (t >= 195) return;
  int r0 = bstart[b], r1 = bstart[b + 1];
  int fb = t * 4;
  float4 acc = {0.f, 0.f, 0.f, 0.f};
  for (int r = r0; r < r1; ++r) {
    uint2 u = *(const uint2*)(x2b + (size_t)r * HP + fb);
    acc.x += us2f((unsigned short)(u.x & 0xffffu));
    acc.y += us2f((unsigned short)(u.x >> 16));
    acc.z += us2f((unsigned short)(u.y & 0xffffu));
    acc.w += us2f((unsigned short)(u.y >> 16));
  }
  *(float4*)&xg_pool[(size_t)b * HIDD + fb] = acc;
}

// ---------- conv via LUT -> K-major cT[KFXT][MB2]
__global__ __launch_bounds__(256) void k_convT(const int* target, const float* Mtab,
                                               const void* cb, bf16* cT, int* diag) {
  __shared__ int tg[GB * 40];
  __shared__ float Mt[KSZ * VOCS];
  int tt0 = blockIdx.x * 32, o = blockIdx.y, t = threadIdx.x;
  int mode = diag[1];
  for (int e = t; e < KSZ * VOCS; e += 256)
    Mt[e] = Mtab[(o * KSZ + e / VOCS) * VOCS + (e % VOCS)];
  for (int e = t; e < GB * 40; e += 256) {
    int b = e / 40, q = e % 40;
    int pos = tt0 + q;
    int tv = (pos < SEQL) ? target[b * SEQL + pos] : 0;
    if ((unsigned)tv >= VOCS) { atomicOr(diag, 8192); tv = 0; }
    tg[e] = tv;
  }
  __syncthreads();
  float cbv = ldany(cb, o, mode);
  for (int e = t; e < 32 * MB2; e += 256) {
    int tt = e / MB2, b = e % MB2;
    int gtt = tt0 + tt;
    if (gtt >= COUT) continue;
    float acc = 0.f;
    if (b < GB) {
#pragma unroll
      for (int k = 0; k < KSZ; ++k)
        acc += Mt[k * VOCS + tg[b * 40 + tt + k]];
      acc += cbv;
      if (nanf_(acc)) atomicOr(diag, 4096);
    }
    cT[((size_t)o * COUT + gtt) * MB2 + b] = __float2bfloat16(b < GB ? acc : 0.f);
  }
}

// ---------- final 128->1 + diag encoding
__global__ __launch_bounds__(64) void k_out(const float* xf4, const void* o_W,
                                            const void* o_b, void* outp, const int* diag) {
  int b = blockIdx.x, lane = threadIdx.x;
  int mode = diag[1];
  float a0 = fmaxf(xf4[b * 128 + lane], 0.f);
  float a1 = fmaxf(xf4[b * 128 + 64 + lane], 0.f);
  float v = a0 * ldany(o_W, lane, mode) + a1 * ldany(o_W, 64 + lane, mode);
  for (int off = 32; off; off >>= 1) v += __shfl_down(v, off, 64);
  if (lane == 0) {
    float r = v + ldany(o_b, 0, mode);
    int dg = diag[0];
    if (dg) r = 256.f * (1 + mode) + 8.f * (float)(__ffs(dg) - 1);
    else if (nanf_(r)) r = 200.f + 100.f * mode;
    if (mode) ((float*)outp)[b] = r;
    else ((bf16*)outp)[b] = __float2bfloat16(r);
  }
}

extern "C" void kernel_launch(void* const* d_in, const int* in_sizes, int n_in,
                              void* d_out, int out_size, void* d_ws, size_t ws_size,
                              hipStream_t stream) {
  const void* x       = d_in[0];
  const int*  ei      = (const int*)d_in[1];
  const int*  batch   = (const int*)d_in[2];
  const int*  target  = (const int*)d_in[3];
  const void* gat_W   = d_in[4];
  const void* a_src   = d_in[5];
  const void* a_dst   = d_in[6];
  const void* gat_b   = d_in[7];
  const void* gcn_W   = d_in[8];
  const void* gcn_b   = d_in[9];
  const void* fcg1_W  = d_in[10];
  const void* fcg1_b  = d_in[11];
  const void* fcg2_W  = d_in[12];
  const void* fcg2_b  = d_in[13];
  const void* emb     = d_in[14];
  const void* cW      = d_in[15];
  const void* cb      = d_in[16];
  const void* fxt_W   = d_in[17];
  const void* fxt_b   = d_in[18];
  const void* f1_W    = d_in[19];
  const void* f1_b    = d_in[20];
  const void* f2_W    = d_in[21];
  const void* f2_b    = d_in[22];
  const void* f3_W    = d_in[23];
  const void* f3_b    = d_in[24];
  const void* f4_W    = d_in[25];
  const void* f4_b    = d_in[26];
  const void* o_W     = d_in[27];
  const void* o_b     = d_in[28];

  char* w = (char*)d_ws;
  size_t off = 0;
  auto alloc = [&](size_t bytes) -> void* {
    void* p = w + off;
    off = (off + bytes + 255) & ~(size_t)255;
    return p;
  };
  bf16*  h_buf   = (bf16*)alloc((size_t)NODES * HP * 2);    // h2 (stride HP)
  bf16*  x1p     = (bf16*)alloc((size_t)MPAD * KP2 * 2);    // x1 padded; REUSED as x2b
  bf16*  aggx    = (bf16*)alloc((size_t)MPAD * AGS * 2);    // 38.6 MB; REUSED for cT+part
  bf16*  gatWt2  = (bf16*)alloc((size_t)HEADS * 128 * HK * 2);
  bf16*  gcnWt   = (bf16*)alloc((size_t)NPADB * KP2 * 2);
  float* a_s     = (float*)alloc((size_t)NODES * HEADS * 4);
  float* a_d     = (float*)alloc((size_t)NODES * HEADS * 4);
  float* Ws      = (float*)alloc(FD * HEADS * 4);
  float* Wd      = (float*)alloc(FD * HEADS * 4);
  float* Mtab    = (float*)alloc(NFC * KSZ * VOCS * 4);
  int*   rowst   = (int*)alloc((NODES + 1) * 4);
  float* dinv    = (float*)alloc(NODES * 4);
  int*   bstart  = (int*)alloc((GB + 1) * 4);
  float* xg_pool = (float*)alloc((size_t)GB * HIDD * 4);    // fully written by k_pool
  // ---- contiguous zero-initialized region (single memset) ----
  size_t zoff = off;
  int*   cnt     = (int*)alloc(NODES * 4);
  int*   cur     = (int*)alloc(NODES * 4);
  int*   es_src  = (int*)alloc((size_t)ETOT * 4);
  float* xg1     = (float*)alloc((size_t)GB * 1500 * 4);
  float* xc      = (float*)alloc((size_t)GB * 256 * 4);
  float* xf1     = (float*)alloc((size_t)GB * 1024 * 4);
  float* xf2     = (float*)alloc((size_t)GB * 512 * 4);
  float* xf3     = (float*)alloc((size_t)GB * 256 * 4);
  float* xf4     = (float*)alloc((size_t)GB * 128 * 4);
  int*   diag    = (int*)alloc(2 * 4);
  size_t zlen = off - zoff;

  bf16* x2b = x1p;  // x1p dead after gemm2; reuse (stride HP == KP2)
  bf16*  cT   = (bf16*)aggx;
  size_t cTb  = ((size_t)KFXT * MB2 * 2 + 255) & ~(size_t)255;
  float* part = (float*)((char*)aggx + cTb);

  hipMemsetAsync(w + zoff, 0, zlen, stream);

  k_detect<<<1, 256, 0, stream>>>(x, diag);

  k_tr_gcnw<<<dim3(KP2 / 32, NPADB / 32), 256, 0, stream>>>(gcn_W, gcnWt, diag);
  k_prepg<<<(HEADS * 128 * HK + 255) / 256, 256, 0, stream>>>(gat_W, a_src, a_dst,
                                                              Ws, Wd, gatWt2, diag);
  k_zero_x1pad<<<((MPAD - NODES) * KP2 + NODES * 20 + 255) / 256, 256, 0, stream>>>(x1p);
  k_prep_mtab<<<(NFC * KSZ * VOCS + 255) / 256, 256, 0, stream>>>(emb, cW, Mtab, diag);

  k_asd<<<(NODES + 255) / 256, 256, 0, stream>>>(x, Ws, Wd, a_s, a_d, diag);

  // CSR + metadata
  k_count<<<(ETOT + 255) / 256, 256, 0, stream>>>(ei, cnt, diag);
  k_scan<<<1, 1024, 0, stream>>>(cnt, rowst);
  k_scatter<<<(ETOT + 255) / 256, 256, 0, stream>>>(ei, rowst, cur, es_src, diag);
  k_graphmeta<<<(NODES + 255) / 256, 256, 0, stream>>>(cnt, cur, rowst, batch,
                                                       dinv, bstart, diag);

  // fused softmax + x-space GAT gather, then per-head MFMA GEMM
  k_gatx<<<NODES, 64, 0, stream>>>(es_src, rowst, a_s, a_d, x, aggx, diag);
  k_hgemm<<<dim3(MPAD / MT, HEADS), 256, 0, stream>>>(aggx, gatWt2, gat_b, x1p, diag);

  // h2 = x1 @ gcn_W  (MFMA, stride HP)
  k_gemm_mfma<<<dim3(NPADB / NT, MPAD / MT), 256, 0, stream>>>(
      x1p, KP2, gcnWt, KP2, h_buf, HP, HP, NODES, KP2);

  // panel-major GCN gather -> x2b, then sorted-segment pool
  k_gcng<<<NODES * PNL, 64, 0, stream>>>(es_src, rowst, dinv, h_buf, gcn_b, x2b, diag);
  k_pool<<<GB, 256, 0, stream>>>(x2b, bstart, xg_pool);

  // conv -> K-major cT (aliases aggx), then streaming fxt + reduce
  k_convT<<<dim3((COUT + 31) / 32, NFC), 256, 0, stream>>>(target, Mtab, cb, cT, diag);
  k_fxt<<<dim3(2, FXT_KS), 256, 0, stream>>>(cT, fxt_W, part, diag);
  k_fxt_red<<<GB, 128, 0, stream>>>(part, fxt_b, xc, diag);

  // graph MLP head + fusion MLP via MFMA
  k_mlp_mfma<<<dim3(24, 4), 256, 0, stream>>>(xg_pool, HIDD, fcg1_W, fcg1_b,
                                              xg1, 1500, 0, GB, 1500, HIDD, 4, 0, 0, diag);
  k_mlp_mfma<<<dim3(2, 16), 256, 0, stream>>>(xg1, 1500, fcg2_W, fcg2_b,
                                              xc, 256, 0, GB, 128, 1500, 16, 1, 0, diag);
  k_mlp_mfma<<<dim3(16, 4), 256, 0, stream>>>(xc, 256, f1_W, f1_b,
                                              xf1, 1024, 0, GB, 1024, 256, 4, 0, 0, diag);
  k_mlp_mfma<<<dim3(8, 8), 256, 0, stream>>>(xf1, 1024, f2_W, f2_b,
                                             xf2, 512, 0, GB, 512, 1024, 8, 1, 0, diag);
  k_mlp_mfma<<<dim3(4, 8), 256, 0, stream>>>(xf2, 512, f3_W, f3_b,
                                             xf3, 256, 0, GB, 256, 512, 8, 1, 0, diag);
  k_mlp_mfma<<<dim3(2, 8), 256, 0, stream>>>(xf3, 256, f4_W, f4_b,
                                             xf4, 128, 0, GB, 128, 256, 8, 1, 0, diag);
  k_out<<<GB, 64, 0, stream>>>(xf4, o_W, o_b, d_out, diag);
}

// Round 16
// 843.271 us; speedup vs baseline: 1.0151x; 1.0151x over previous
//
#include <hip/hip_runtime.h>
#include <hip/hip_bf16.h>
#include <math.h>

typedef __hip_bfloat16 bf16;
typedef __attribute__((ext_vector_type(8))) short short8v;   // 8 bf16 (4 VGPRs)
typedef __attribute__((ext_vector_type(4))) float float4v;   // mfma acc

#define NODES 20000
#define EDG   400000
#define ETOT  (EDG + NODES)
#define GB    200
#define HEADS 10
#define FD    78
#define HIDD  780
#define SEQL  1000
#define VOCS  26
#define EMBD  128
#define NFC   32
#define KSZ   8
#define COUT  993
#define KFXT  (NFC * COUT)

#define MPAD  20096   // 157*128
#define NPADB 896     // 7*128
#define KP2   800     // K=780 padded to 25*32
#define HP    800     // h2/x2 row stride == KP2; 2 panels x 400 feats
#define PNL   2
#define PF    400     // feats per panel = 50 lanes x 8
#define MB2   208     // padded batch rows (13*16) for fxt / cT
#define FXT_KS 128    // fxt K-split blocks per n-tile
#define HK    96      // per-head K pad (78 -> 96)
#define AGS   960     // aggx row stride = HEADS * HK

// diag[0] bits: 1=CSR structural, 2=gat den NaN, 8=gat acc NaN, 16=gcn acc NaN,
// 4096=conv NaN, 8192=idx OOB
// diag[1]: 0 = inputs are bf16, 1 = inputs are fp32

__device__ __forceinline__ float us2f(unsigned short u) {
  unsigned int i = ((unsigned int)u) << 16; float f; __builtin_memcpy(&f, &i, 4); return f;
}
__device__ __forceinline__ float b2f(bf16 v) { return __bfloat162float(v); }
__device__ __forceinline__ float ldany(const void* p, size_t i, int m) {
  if (m) return ((const float*)p)[i];
  return b2f(((const bf16*)p)[i]);
}
__device__ __forceinline__ bool nanf_(float v) { return v != v; }
__device__ __forceinline__ unsigned short f2us(float v) {
  bf16 b = __float2bfloat16(v); unsigned short u; __builtin_memcpy(&u, &b, 2); return u;
}

// ---------- runtime dtype detection on x
__global__ void k_detect(const void* x, int* diag) {
  int t = threadIdx.x;
  const unsigned short* u = (const unsigned short*)x;
  int hit = 0;
  for (int i = t; i < 4096; i += 256) {
    float v = us2f(u[i]);
    if (nanf_(v) || fabsf(v) > 1e6f) hit = 1;
  }
  if (hit) diag[1] = 1;  // benign race
}

// ---------- LDS-tiled transpose gcn_W [780][780] -> gcnWt[NPADB][KP2]
__global__ __launch_bounds__(256) void k_tr_gcnw(const void* gw, bf16* Wt,
                                                 const int* diag) {
  __shared__ float tile[32][33];
  int k0 = blockIdx.x * 32, n0 = blockIdx.y * 32;
  int mode = diag[1];
  int t = threadIdx.x;
  int tn = t & 31, tk = t >> 5;  // 8 rows per pass
  for (int kk = tk; kk < 32; kk += 8) {
    int gk = k0 + kk, gn = n0 + tn;
    tile[kk][tn] = (gk < HIDD && gn < HIDD) ? ldany(gw, (size_t)gk * HIDD + gn, mode) : 0.f;
  }
  __syncthreads();
  for (int nn = tk; nn < 32; nn += 8) {
    int gn = n0 + nn, gk = k0 + tn;
    if (gn < NPADB && gk < KP2)
      Wt[(size_t)gn * KP2 + gk] = __float2bfloat16(tile[tn][nn]);
  }
}

// ---------- merged GAT prep: fold gat_a (idx<780) + per-head Wt2 (idx<122880)
__global__ void k_prepg(const void* gat_W, const void* a_src, const void* a_dst,
                        float* Ws, float* Wd, bf16* Wt2, const int* diag) {
  int idx = blockIdx.x * 256 + threadIdx.x;
  int mode = diag[1];
  if (idx < FD * HEADS) {
    int k = idx / HEADS, hd = idx % HEADS;
    float s = 0.f, d = 0.f;
    for (int f = 0; f < FD; ++f) {
      float w = ldany(gat_W, (size_t)k * HIDD + hd * FD + f, mode);
      s += w * ldany(a_src, (size_t)hd * FD + f, mode);
      d += w * ldany(a_dst, (size_t)hd * FD + f, mode);
    }
    Ws[idx] = s;
    Wd[idx] = d;
  }
  if (idx < HEADS * 128 * HK) {
    int h = idx / (128 * HK);
    int r = idx % (128 * HK);
    int n = r / HK, k = r % HK;
    float v = (n < FD && k < FD) ? ldany(gat_W, (size_t)k * HIDD + h * FD + n, mode) : 0.f;
    Wt2[idx] = __float2bfloat16(v);
  }
}

// ---------- zero x1p pad rows (>= NODES) and pad cols [780, 800)
__global__ void k_zero_x1pad(bf16* x1p) {
  int i = blockIdx.x * 256 + threadIdx.x;
  int nr = (MPAD - NODES) * KP2;  // 76800
  if (i < nr) {
    x1p[(size_t)NODES * KP2 + i] = __float2bfloat16(0.f);
  } else {
    int j = i - nr;
    if (j < NODES * 20) {
      int d = j / 20, c = HIDD + (j % 20);
      x1p[(size_t)d * KP2 + c] = __float2bfloat16(0.f);
    }
  }
}

// ---------- MFMA bf16 GEMM: C[gm*ldc+gn] = A[M x Kp (lda)] @ Bt[n][k] (ldb)
#define MT 128
#define NT 128
#define BK 32
#define LP 40
__global__ __launch_bounds__(256) void k_gemm_mfma(const bf16* A, int lda,
                                                   const bf16* Bt, int ldb,
                                                   bf16* C, int ldc, int Ncap,
                                                   int M, int Kp) {
  __shared__ __align__(16) bf16 As[MT * LP];
  __shared__ __align__(16) bf16 Bs[NT * LP];
  int t = threadIdx.x;
  int lane = t & 63, w = t >> 6;
  int wr = (w >> 1) * 64, wc = (w & 1) * 64;
  int quad = lane >> 4, mr = lane & 15;
  int m0 = blockIdx.y * MT, n0 = blockIdx.x * NT;
  float4v acc[4][4];
#pragma unroll
  for (int i = 0; i < 4; ++i)
#pragma unroll
    for (int j = 0; j < 4; ++j) acc[i][j] = (float4v){0.f, 0.f, 0.f, 0.f};

  for (int kc = 0; kc < Kp; kc += BK) {
#pragma unroll
    for (int i = 0; i < 4; ++i) {
      int c = t + i * 256;
      int row = c >> 3, col = (c & 7) * 4;
      *(uint2*)&As[row * LP + col] =
          *(const uint2*)&A[(size_t)(m0 + row) * lda + kc + col];
      *(uint2*)&Bs[row * LP + col] =
          *(const uint2*)&Bt[(size_t)(n0 + row) * ldb + kc + col];
    }
    __syncthreads();
    short8v af[4], bfr[4];
#pragma unroll
    for (int i = 0; i < 4; ++i)
      af[i] = *(const short8v*)&As[(wr + i * 16 + mr) * LP + quad * 8];
#pragma unroll
    for (int j = 0; j < 4; ++j)
      bfr[j] = *(const short8v*)&Bs[(wc + j * 16 + mr) * LP + quad * 8];
#pragma unroll
    for (int i = 0; i < 4; ++i)
#pragma unroll
      for (int j = 0; j < 4; ++j)
        acc[i][j] = __builtin_amdgcn_mfma_f32_16x16x32_bf16(af[i], bfr[j], acc[i][j], 0, 0, 0);
    __syncthreads();
  }
#pragma unroll
  for (int i = 0; i < 4; ++i) {
    int gm0 = m0 + wr + i * 16 + quad * 4;
#pragma unroll
    for (int j = 0; j < 4; ++j) {
      int gn = n0 + wc + j * 16 + mr;
      if (gn >= Ncap) continue;
#pragma unroll
      for (int r = 0; r < 4; ++r) {
        int gm = gm0 + r;
        if (gm < M) C[(size_t)gm * ldc + gn] = __float2bfloat16(acc[i][j][r]);
      }
    }
  }
}

// ---------- per-head GAT GEMM: x1[d][h*78+n] = relu(aggx[d][h] @ W_h + b)
__global__ __launch_bounds__(256) void k_hgemm(const bf16* aggx, const bf16* Wt2,
                                               const void* gat_b, bf16* x1,
                                               const int* diag) {
  __shared__ __align__(16) bf16 As[MT * LP];
  __shared__ __align__(16) bf16 Bs[NT * LP];
  int t = threadIdx.x;
  int lane = t & 63, w = t >> 6;
  int wr = (w >> 1) * 64, wc = (w & 1) * 64;
  int quad = lane >> 4, mr = lane & 15;
  int m0 = blockIdx.x * MT, h = blockIdx.y;
  int mode = diag[1];
  const bf16* A = aggx + (size_t)h * HK;
  const bf16* Bt = Wt2 + (size_t)h * 128 * HK;
  float4v acc[4][4];
#pragma unroll
  for (int i = 0; i < 4; ++i)
#pragma unroll
    for (int j = 0; j < 4; ++j) acc[i][j] = (float4v){0.f, 0.f, 0.f, 0.f};

  for (int kc = 0; kc < HK; kc += BK) {
#pragma unroll
    for (int i = 0; i < 4; ++i) {
      int c = t + i * 256;
      int row = c >> 3, col = (c & 7) * 4;
      *(uint2*)&As[row * LP + col] =
          *(const uint2*)&A[(size_t)(m0 + row) * AGS + kc + col];
      *(uint2*)&Bs[row * LP + col] =
          *(const uint2*)&Bt[(size_t)row * HK + kc + col];
    }
    __syncthreads();
    short8v af[4], bfr[4];
#pragma unroll
    for (int i = 0; i < 4; ++i)
      af[i] = *(const short8v*)&As[(wr + i * 16 + mr) * LP + quad * 8];
#pragma unroll
    for (int j = 0; j < 4; ++j)
      bfr[j] = *(const short8v*)&Bs[(wc + j * 16 + mr) * LP + quad * 8];
#pragma unroll
    for (int i = 0; i < 4; ++i)
#pragma unroll
      for (int j = 0; j < 4; ++j)
        acc[i][j] = __builtin_amdgcn_mfma_f32_16x16x32_bf16(af[i], bfr[j], acc[i][j], 0, 0, 0);
    __syncthreads();
  }
#pragma unroll
  for (int i = 0; i < 4; ++i) {
    int gm0 = m0 + wr + i * 16 + quad * 4;
#pragma unroll
    for (int j = 0; j < 4; ++j) {
      int gn = wc + j * 16 + mr;
      if (gn >= FD) continue;
      float bs = ldany(gat_b, h * FD + gn, mode);
#pragma unroll
      for (int r = 0; r < 4; ++r) {
        int gm = gm0 + r;
        if (gm < NODES)
          x1[(size_t)gm * KP2 + h * FD + gn] =
              __float2bfloat16(fmaxf(acc[i][j][r] + bs, 0.f));
      }
    }
  }
}

// ---------- MFMA small-M dense layer (generic; all MLP layers but fxt)
#define MLP_NT 64
#define MLP_BK 32
#define MLP_MT 208
#define MLP_LP 40
__global__ __launch_bounds__(256) void k_mlp_mfma(const void* A, int lda, const void* Bw,
                                                  const void* bias, float* out, int ostride,
                                                  int ooff, int M, int Nn, int K,
                                                  int ksplit, int aRelu, int aBf16,
                                                  const int* diag) {
  __shared__ __align__(16) bf16 As[MLP_MT * MLP_LP];
  __shared__ __align__(16) bf16 Bs[MLP_NT * MLP_LP];
  int mode = diag[1];
  int t = threadIdx.x;
  int lane = t & 63, w = t >> 6;
  int quad = lane >> 4, mr = lane & 15;
  int n0 = blockIdx.x * MLP_NT;
  int kz = blockIdx.y;
  int nchunks = (K + MLP_BK - 1) / MLP_BK;
  int cpk = (nchunks + ksplit - 1) / ksplit;
  int c0 = kz * cpk, c1 = c0 + cpk;
  if (c1 > nchunks) c1 = nchunks;
  float4v acc[13];
#pragma unroll
  for (int i = 0; i < 13; ++i) acc[i] = (float4v){0.f, 0.f, 0.f, 0.f};

  for (int c = c0; c < c1; ++c) {
    int k0 = c * MLP_BK;
    if (aBf16) {
      const bf16* Ab = (const bf16*)A;
      for (int e = t; e < MLP_MT * 4; e += 256) {
        int row = e >> 2, c8 = (e & 3) * 8;
        int gk = k0 + c8;
        if (row < M && gk + 7 < K) {
          *(uint4*)&As[row * MLP_LP + c8] = *(const uint4*)&Ab[(size_t)row * lda + gk];
        } else {
#pragma unroll
          for (int kk = 0; kk < 8; ++kk) {
            float v = (row < M && gk + kk < K) ? b2f(Ab[(size_t)row * lda + gk + kk]) : 0.f;
            As[row * MLP_LP + c8 + kk] = __float2bfloat16(v);
          }
        }
      }
    } else {
      const float* Af = (const float*)A;
      for (int e = t; e < MLP_MT * 8; e += 256) {
        int row = e >> 3, c4 = (e & 7) * 4;
        int gk = k0 + c4;
        float4 v4 = {0.f, 0.f, 0.f, 0.f};
        if (row < M) {
          if (gk + 3 < K) {
            v4 = *(const float4*)&Af[(size_t)row * lda + gk];
          } else {
            v4.x = (gk + 0 < K) ? Af[(size_t)row * lda + gk + 0] : 0.f;
            v4.y = (gk + 1 < K) ? Af[(size_t)row * lda + gk + 1] : 0.f;
            v4.z = (gk + 2 < K) ? Af[(size_t)row * lda + gk + 2] : 0.f;
            v4.w = (gk + 3 < K) ? Af[(size_t)row * lda + gk + 3] : 0.f;
          }
        }
        if (aRelu) {
          v4.x = fmaxf(v4.x, 0.f); v4.y = fmaxf(v4.y, 0.f);
          v4.z = fmaxf(v4.z, 0.f); v4.w = fmaxf(v4.w, 0.f);
        }
        bf16* dst = &As[row * MLP_LP + c4];
        dst[0] = __float2bfloat16(v4.x); dst[1] = __float2bfloat16(v4.y);
        dst[2] = __float2bfloat16(v4.z); dst[3] = __float2bfloat16(v4.w);
      }
    }
    for (int e = t; e < MLP_NT * MLP_BK; e += 256) {
      int k = e >> 6, col = e & 63;
      int gk = k0 + k, gn = n0 + col;
      float v = (gn < Nn && gk < K) ? ldany(Bw, (size_t)gk * Nn + gn, mode) : 0.f;
      Bs[col * MLP_LP + k] = __float2bfloat16(v);
    }
    __syncthreads();
    short8v bf = *(const short8v*)&Bs[(w * 16 + mr) * MLP_LP + quad * 8];
#pragma unroll
    for (int i = 0; i < 13; ++i) {
      short8v af = *(const short8v*)&As[(i * 16 + mr) * MLP_LP + quad * 8];
      acc[i] = __builtin_amdgcn_mfma_f32_16x16x32_bf16(af, bf, acc[i], 0, 0, 0);
    }
    __syncthreads();
  }
  int gn = n0 + w * 16 + mr;
  if (gn >= Nn) return;
  float bs = (kz == 0) ? ldany(bias, gn, mode) : 0.f;
#pragma unroll
  for (int i = 0; i < 13; ++i) {
    int gm0 = i * 16 + quad * 4;
#pragma unroll
    for (int r = 0; r < 4; ++r) {
      int gm = gm0 + r;
      if (gm >= M) break;
      float v = acc[i][r] + bs;
      float* op = &out[(size_t)gm * ostride + ooff + gn];
      if (ksplit == 1) *op = v;
      else atomicAdd(op, v);
    }
  }
}

// ---------- dedicated fxt: partials = cT[K x 208] @ fxt_W[K x 128]
__global__ __launch_bounds__(256) void k_fxt(const bf16* cT, const void* Bw,
                                             float* part, const int* diag) {
  __shared__ __align__(16) bf16 As[MLP_MT * MLP_LP];
  __shared__ __align__(16) bf16 Bs[MLP_NT * MLP_LP];
  int mode = diag[1];
  int t = threadIdx.x;
  int lane = t & 63, w = t >> 6;
  int quad = lane >> 4, mr = lane & 15;
  int n0 = blockIdx.x * MLP_NT;
  int kz = blockIdx.y;
  int nchunks = KFXT / MLP_BK;                 // 993
  int cpk = (nchunks + FXT_KS - 1) / FXT_KS;   // 8
  int c0 = kz * cpk, c1 = c0 + cpk;
  if (c1 > nchunks) c1 = nchunks;
  float4v acc[13];
#pragma unroll
  for (int i = 0; i < 13; ++i) acc[i] = (float4v){0.f, 0.f, 0.f, 0.f};

  for (int c = c0; c < c1; ++c) {
    int k0 = c * MLP_BK;
    for (int e = t; e < 32 * 52; e += 256) {
      int kk = e / 52, bq = e % 52;
      uint2 u = *(const uint2*)&cT[(size_t)(k0 + kk) * MB2 + bq * 4];
      unsigned short* ap = (unsigned short*)As;
      int mb = bq * 4;
      ap[(mb + 0) * MLP_LP + kk] = (unsigned short)(u.x & 0xffffu);
      ap[(mb + 1) * MLP_LP + kk] = (unsigned short)(u.x >> 16);
      ap[(mb + 2) * MLP_LP + kk] = (unsigned short)(u.y & 0xffffu);
      ap[(mb + 3) * MLP_LP + kk] = (unsigned short)(u.y >> 16);
    }
    for (int e = t; e < MLP_NT * MLP_BK; e += 256) {
      int k = e >> 6, col = e & 63;
      float v = ldany(Bw, (size_t)(k0 + k) * 128 + (n0 + col), mode);
      Bs[col * MLP_LP + k] = __float2bfloat16(v);
    }
    __syncthreads();
    short8v bf = *(const short8v*)&Bs[(w * 16 + mr) * MLP_LP + quad * 8];
#pragma unroll
    for (int i = 0; i < 13; ++i) {
      short8v af = *(const short8v*)&As[(i * 16 + mr) * MLP_LP + quad * 8];
      acc[i] = __builtin_amdgcn_mfma_f32_16x16x32_bf16(af, bf, acc[i], 0, 0, 0);
    }
    __syncthreads();
  }
  int gnl = n0 + w * 16 + mr;
#pragma unroll
  for (int i = 0; i < 13; ++i) {
#pragma unroll
    for (int r = 0; r < 4; ++r) {
      int gm = i * 16 + quad * 4 + r;
      part[((size_t)kz * MB2 + gm) * 128 + gnl] = acc[i][r];
    }
  }
}

// ---------- fxt partial reduction + bias -> xc[:, 128:256]
__global__ __launch_bounds__(128) void k_fxt_red(const float* part, const void* bias,
                                                 float* xc, const int* diag) {
  int gm = blockIdx.x, n = threadIdx.x;
  int mode = diag[1];
  float s = 0.f;
  for (int kz = 0; kz < FXT_KS; ++kz)
    s += part[((size_t)kz * MB2 + gm) * 128 + n];
  xc[(size_t)gm * 256 + 128 + n] = s + ldany(bias, n, mode);
}

// ---------- conv LUT
__global__ void k_prep_mtab(const void* emb, const void* cW, float* Mtab, const int* diag) {
  int idx = blockIdx.x * 256 + threadIdx.x;
  if (idx >= NFC * KSZ * VOCS) return;
  int mode = diag[1];
  int o = idx / (KSZ * VOCS);
  int r = idx % (KSZ * VOCS);
  int k = r / VOCS, v = r % VOCS;
  float acc = 0.f;
  for (int i = 0; i < EMBD; ++i)
    acc += ldany(emb, (size_t)v * EMBD + i, mode) * ldany(cW, ((size_t)o * EMBD + i) * KSZ + k, mode);
  Mtab[idx] = acc;
}

// ---------- a_s = x @ Ws, a_d = x @ Wd
__global__ __launch_bounds__(256) void k_asd(const void* x, const float* Ws, const float* Wd,
                                             float* a_s, float* a_d, const int* diag) {
  __shared__ unsigned short xs[256 * FD];
  __shared__ float ws_sh[FD * HEADS], wd_sh[FD * HEADS];
  int mode = diag[1];
  int nb = blockIdx.x * 256, t = threadIdx.x;
  for (int e = t; e < FD * HEADS; e += 256) { ws_sh[e] = Ws[e]; wd_sh[e] = Wd[e]; }
  for (int e = t; e < 256 * FD; e += 256) {
    int r = e / FD, c = e % FD;
    int gn = nb + r;
    float xv = (gn < NODES) ? ldany(x, (size_t)gn * FD + c, mode) : 0.f;
    xs[e] = f2us(xv);
  }
  __syncthreads();
  int n = nb + t;
  if (n >= NODES) return;
  float as[HEADS], ad[HEADS];
#pragma unroll
  for (int hd = 0; hd < HEADS; ++hd) { as[hd] = 0.f; ad[hd] = 0.f; }
  for (int f = 0; f < FD; ++f) {
    float xv = us2f(xs[t * FD + f]);
#pragma unroll
    for (int hd = 0; hd < HEADS; ++hd) {
      as[hd] += xv * ws_sh[f * HEADS + hd];
      ad[hd] += xv * wd_sh[f * HEADS + hd];
    }
  }
#pragma unroll
  for (int hd = 0; hd < HEADS; ++hd) {
    a_s[n * HEADS + hd] = as[hd];
    a_d[n * HEADS + hd] = ad[hd];
  }
}

// ---------- CSR build
__global__ void k_count(const int* ei, int* cnt, int* diag) {
  int e = blockIdx.x * 256 + threadIdx.x;
  if (e >= ETOT) return;
  int d = (e < EDG) ? ei[EDG + e] : (e - EDG);
  if ((unsigned)d >= NODES) { atomicOr(diag, 8192); d = 0; }
  atomicAdd(&cnt[d], 1);
}

// shfl-based block scan
__global__ __launch_bounds__(1024) void k_scan(const int* cnt, int* rowstart) {
  __shared__ int wsum[16];
  __shared__ int carry;
  int t = threadIdx.x;
  int lane = t & 63, wid = t >> 6;
  if (t == 0) carry = 0;
  __syncthreads();
  for (int c = 0; c < (NODES + 1023) / 1024; ++c) {
    int i = c * 1024 + t;
    int orig = (i < NODES) ? cnt[i] : 0;
    int v = orig;
#pragma unroll
    for (int off = 1; off < 64; off <<= 1) {
      int u = __shfl_up(v, off, 64);
      if (lane >= off) v += u;
    }
    if (lane == 63) wsum[wid] = v;
    __syncthreads();
    if (t == 0) {
      int s = carry;
      for (int j = 0; j < 16; ++j) { int tmp = wsum[j]; wsum[j] = s; s += tmp; }
      carry = s;
    }
    __syncthreads();
    if (i < NODES) rowstart[i] = v - orig + wsum[wid];
    __syncthreads();
  }
  if (t == 0) rowstart[NODES] = carry;
}

__global__ void k_scatter(const int* ei, const int* rowstart, int* cur, int* es_src,
                          int* diag) {
  int e = blockIdx.x * 256 + threadIdx.x;
  if (e >= ETOT) return;
  int s, d;
  if (e < EDG) { s = ei[e]; d = ei[EDG + e]; } else { s = e - EDG; d = s; }
  if ((unsigned)d >= NODES) { atomicOr(diag, 8192); d = 0; }
  if ((unsigned)s >= NODES) { atomicOr(diag, 8192); s = 0; }
  int pos = rowstart[d] + atomicAdd(&cur[d], 1);
  if ((unsigned)pos < (unsigned)ETOT) es_src[pos] = s;
  else atomicOr(diag, 1);
}

// ---------- merged: dinv + CSR check + batch segment starts
__global__ void k_graphmeta(const int* cnt, const int* cur, const int* rowst,
                            const int* batch, float* dinv, int* bstart, int* diag) {
  int n = blockIdx.x * 256 + threadIdx.x;
  if (n >= NODES) return;
  int dg = cnt[n];
  dinv[n] = rsqrtf((float)(dg > 0 ? dg : 1));
  if (cur[n] != cnt[n]) atomicOr(diag, 1);
  if (n == 0 && rowst[NODES] != ETOT) atomicOr(diag, 1);
  int bi = batch[n];
  if ((unsigned)bi >= GB) { atomicOr(diag, 8192); bi = GB - 1; }
  int bp;
  if (n == 0) bp = -1;
  else {
    bp = batch[n - 1];
    if ((unsigned)bp >= GB) bp = GB - 1;
  }
  for (int b = bp + 1; b <= bi; ++b) bstart[b] = n;
  if (n == NODES - 1)
    for (int b = bi + 1; b <= GB; ++b) bstart[b] = NODES;
}

// ---------- FUSED GAT softmax + x-space gather
__global__ __launch_bounds__(64) void k_gatx(const int* es_src, const int* rowst,
                                             const float* a_s, const float* a_d,
                                             const void* x, bf16* aggx, int* diag) {
  __shared__ int ssc[64];
  __shared__ float alw[64 * HEADS];
  int d = blockIdx.x, lane = threadIdx.x;
  int mode = diag[1];
  int start = rowst[d], end = rowst[d + 1];
  float ad[HEADS];
#pragma unroll
  for (int j = 0; j < HEADS; ++j) ad[j] = a_d[d * HEADS + j];

  float mx[HEADS];
#pragma unroll
  for (int j = 0; j < HEADS; ++j) mx[j] = -INFINITY;
  for (int base = start; base < end; base += 64) {
    int ce = base + lane;
    if (ce < end) {
      int s = es_src[ce];
      if ((unsigned)s >= NODES) { atomicOr(diag, 1); s = 0; }
#pragma unroll
      for (int j = 0; j < HEADS; ++j) {
        float v = a_s[s * HEADS + j] + ad[j];
        v = v > 0.f ? v : 0.2f * v;
        mx[j] = fmaxf(mx[j], v);
      }
    }
  }
#pragma unroll
  for (int j = 0; j < HEADS; ++j)
    for (int off = 1; off < 64; off <<= 1) mx[j] = fmaxf(mx[j], __shfl_xor(mx[j], off, 64));

  float den[HEADS];
#pragma unroll
  for (int j = 0; j < HEADS; ++j) den[j] = 0.f;
  int f0 = 2 * lane;
  float acc[HEADS][2];
#pragma unroll
  for (int j = 0; j < HEADS; ++j) { acc[j][0] = 0.f; acc[j][1] = 0.f; }
  for (int base = start; base < end; base += 64) {
    int ce = base + lane;
    if (ce < end) {
      int s = es_src[ce];
      if ((unsigned)s >= NODES) s = 0;
      ssc[lane] = s;
#pragma unroll
      for (int j = 0; j < HEADS; ++j) {
        float v = a_s[s * HEADS + j] + ad[j];
        v = v > 0.f ? v : 0.2f * v;
        float ex = expf(v - mx[j]);
        alw[lane * HEADS + j] = ex;
        den[j] += ex;
      }
    }
    __syncthreads();
    int cnt2 = end - base; if (cnt2 > 64) cnt2 = 64;
    if (lane < 39) {
      for (int e = 0; e < cnt2; ++e) {
        int ss = ssc[e];
        float xv0, xv1;
        if (mode) {
          const float* xf = (const float*)x;
          xv0 = xf[(size_t)ss * FD + f0];
          xv1 = xf[(size_t)ss * FD + f0 + 1];
        } else {
          unsigned int u = *(const unsigned int*)((const unsigned short*)x +
                                                  (size_t)ss * FD + f0);
          xv0 = us2f((unsigned short)(u & 0xffffu));
          xv1 = us2f((unsigned short)(u >> 16));
        }
        const float* al = &alw[e * HEADS];
#pragma unroll
        for (int j = 0; j < HEADS; ++j) {
          acc[j][0] += al[j] * xv0;
          acc[j][1] += al[j] * xv1;
        }
      }
    }
    __syncthreads();
  }
#pragma unroll
  for (int j = 0; j < HEADS; ++j)
    for (int off = 1; off < 64; off <<= 1) den[j] += __shfl_xor(den[j], off, 64);
  if (lane == 0 && (nanf_(den[0]) || nanf_(den[HEADS - 1]))) atomicOr(diag, 2);

  if (lane < 48) {
    if (lane < 39 && (nanf_(acc[0][0]) || nanf_(acc[HEADS - 1][1]))) atomicOr(diag, 8);
    size_t rb = (size_t)d * AGS;
#pragma unroll
    for (int h = 0; h < HEADS; ++h) {
      float r = 1.f / den[h];
      unsigned short o0 = (f0 < FD) ? f2us(acc[h][0] * r) : (unsigned short)0;
      unsigned short o1 = (f0 + 1 < FD) ? f2us(acc[h][1] * r) : (unsigned short)0;
      unsigned int pack = (unsigned int)o0 | ((unsigned int)o1 << 16);
      *(unsigned int*)(aggx + rb + h * HK + f0) = pack;
    }
  }
}

// ---------- GCN panel gather -> x2b; interleaved ordering (p=bid&1, d=bid>>1)
// [round-15 post-mortem: panel-major grid REGRESSED (+1 µs, +3 MB FETCH); keep interleaved]
__global__ __launch_bounds__(64) void k_gcng(const int* es_src, const int* rowst,
                                             const float* dinv, const bf16* h2,
                                             const void* gcn_b, bf16* x2b, int* diag) {
  __shared__ int ssc[64];
  __shared__ float nw[64];
  int bid = blockIdx.x;
  int p = bid & (PNL - 1), d = bid >> 1;
  int lane = threadIdx.x;
  int mode = diag[1];
  int start = rowst[d], end = rowst[d + 1];
  float dd = dinv[d];
  int fb = p * PF + lane * 8;
  float acc[8];
#pragma unroll
  for (int k = 0; k < 8; ++k) acc[k] = 0.f;
  for (int base = start; base < end; base += 64) {
    int ce = base + lane;
    if (ce < end) {
      int s = es_src[ce];
      if ((unsigned)s >= NODES) { atomicOr(diag, 1); s = 0; }
      ssc[lane] = s;
      nw[lane] = dinv[s] * dd;
    }
    __syncthreads();
    int cnt2 = end - base; if (cnt2 > 64) cnt2 = 64;
    if (lane < 50) {
      for (int e = 0; e < cnt2; ++e) {
        int ss = ssc[e];
        float nv = nw[e];
        uint4 u = *(const uint4*)(h2 + (size_t)ss * HP + fb);
        unsigned int uw[4] = {u.x, u.y, u.z, u.w};
#pragma unroll
        for (int k = 0; k < 4; ++k) {
          acc[2 * k]     += nv * us2f((unsigned short)(uw[k] & 0xffffu));
          acc[2 * k + 1] += nv * us2f((unsigned short)(uw[k] >> 16));
        }
      }
    }
    __syncthreads();
  }
  if (lane < 50) {
    if (nanf_(acc[0]) || nanf_(acc[7])) atomicOr(diag, 16);
    unsigned short o[8];
#pragma unroll
    for (int k = 0; k < 8; ++k) {
      int f = fb + k;
      float v = 0.f;
      if (f < HIDD) v = fmaxf(acc[k] + ldany(gcn_b, f, mode), 0.f);
      o[k] = f2us(v);
    }
    uint4 pack;
    __builtin_memcpy(&pack, o, 16);
    *(uint4*)(x2b + (size_t)d * HP + fb) = pack;
  }
}

// ---------- segment pool: xg_pool[b][f] = sum_{d in segment} x2b[d][f]
__global__ __launch_bounds__(256) void k_pool(const bf16* x2b, const int* bstart,
                                              float* xg_pool) {
  int b = blockIdx.x, t = threadIdx.x;
  if (t >= 195) return;
  int r0 = bstart[b], r1 = bstart[b + 1];
  int fb = t * 4;
  float4 acc = {0.f, 0.f, 0.f, 0.f};
  for (int r = r0; r < r1; ++r) {
    uint2 u = *(const uint2*)(x2b + (size_t)r * HP + fb);
    acc.x += us2f((unsigned short)(u.x & 0xffffu));
    acc.y += us2f((unsigned short)(u.x >> 16));
    acc.z += us2f((unsigned short)(u.y & 0xffffu));
    acc.w += us2f((unsigned short)(u.y >> 16));
  }
  *(float4*)&xg_pool[(size_t)b * HIDD + fb] = acc;
}

// ---------- conv via LUT -> K-major cT[KFXT][MB2]
__global__ __launch_bounds__(256) void k_convT(const int* target, const float* Mtab,
                                               const void* cb, bf16* cT, int* diag) {
  __shared__ int tg[GB * 40];
  __shared__ float Mt[KSZ * VOCS];
  int tt0 = blockIdx.x * 32, o = blockIdx.y, t = threadIdx.x;
  int mode = diag[1];
  for (int e = t; e < KSZ * VOCS; e += 256)
    Mt[e] = Mtab[(o * KSZ + e / VOCS) * VOCS + (e % VOCS)];
  for (int e = t; e < GB * 40; e += 256) {
    int b = e / 40, q = e % 40;
    int pos = tt0 + q;
    int tv = (pos < SEQL) ? target[b * SEQL + pos] : 0;
    if ((unsigned)tv >= VOCS) { atomicOr(diag, 8192); tv = 0; }
    tg[e] = tv;
  }
  __syncthreads();
  float cbv = ldany(cb, o, mode);
  for (int e = t; e < 32 * MB2; e += 256) {
    int tt = e / MB2, b = e % MB2;
    int gtt = tt0 + tt;
    if (gtt >= COUT) continue;
    float acc = 0.f;
    if (b < GB) {
#pragma unroll
      for (int k = 0; k < KSZ; ++k)
        acc += Mt[k * VOCS + tg[b * 40 + tt + k]];
      acc += cbv;
      if (nanf_(acc)) atomicOr(diag, 4096);
    }
    cT[((size_t)o * COUT + gtt) * MB2 + b] = __float2bfloat16(b < GB ? acc : 0.f);
  }
}

// ---------- final 128->1 + diag encoding
__global__ __launch_bounds__(64) void k_out(const float* xf4, const void* o_W,
                                            const void* o_b, void* outp, const int* diag) {
  int b = blockIdx.x, lane = threadIdx.x;
  int mode = diag[1];
  float a0 = fmaxf(xf4[b * 128 + lane], 0.f);
  float a1 = fmaxf(xf4[b * 128 + 64 + lane], 0.f);
  float v = a0 * ldany(o_W, lane, mode) + a1 * ldany(o_W, 64 + lane, mode);
  for (int off = 32; off; off >>= 1) v += __shfl_down(v, off, 64);
  if (lane == 0) {
    float r = v + ldany(o_b, 0, mode);
    int dg = diag[0];
    if (dg) r = 256.f * (1 + mode) + 8.f * (float)(__ffs(dg) - 1);
    else if (nanf_(r)) r = 200.f + 100.f * mode;
    if (mode) ((float*)outp)[b] = r;
    else ((bf16*)outp)[b] = __float2bfloat16(r);
  }
}

extern "C" void kernel_launch(void* const* d_in, const int* in_sizes, int n_in,
                              void* d_out, int out_size, void* d_ws, size_t ws_size,
                              hipStream_t stream) {
  const void* x       = d_in[0];
  const int*  ei      = (const int*)d_in[1];
  const int*  batch   = (const int*)d_in[2];
  const int*  target  = (const int*)d_in[3];
  const void* gat_W   = d_in[4];
  const void* a_src   = d_in[5];
  const void* a_dst   = d_in[6];
  const void* gat_b   = d_in[7];
  const void* gcn_W   = d_in[8];
  const void* gcn_b   = d_in[9];
  const void* fcg1_W  = d_in[10];
  const void* fcg1_b  = d_in[11];
  const void* fcg2_W  = d_in[12];
  const void* fcg2_b  = d_in[13];
  const void* emb     = d_in[14];
  const void* cW      = d_in[15];
  const void* cb      = d_in[16];
  const void* fxt_W   = d_in[17];
  const void* fxt_b   = d_in[18];
  const void* f1_W    = d_in[19];
  const void* f1_b    = d_in[20];
  const void* f2_W    = d_in[21];
  const void* f2_b    = d_in[22];
  const void* f3_W    = d_in[23];
  const void* f3_b    = d_in[24];
  const void* f4_W    = d_in[25];
  const void* f4_b    = d_in[26];
  const void* o_W     = d_in[27];
  const void* o_b     = d_in[28];

  char* w = (char*)d_ws;
  size_t off = 0;
  auto alloc = [&](size_t bytes) -> void* {
    void* p = w + off;
    off = (off + bytes + 255) & ~(size_t)255;
    return p;
  };
  bf16*  h_buf   = (bf16*)alloc((size_t)NODES * HP * 2);    // h2 (stride HP)
  bf16*  x1p     = (bf16*)alloc((size_t)MPAD * KP2 * 2);    // x1 padded; REUSED as x2b
  bf16*  aggx    = (bf16*)alloc((size_t)MPAD * AGS * 2);    // 38.6 MB; REUSED for cT+part
  bf16*  gatWt2  = (bf16*)alloc((size_t)HEADS * 128 * HK * 2);
  bf16*  gcnWt   = (bf16*)alloc((size_t)NPADB * KP2 * 2);
  float* a_s     = (float*)alloc((size_t)NODES * HEADS * 4);
  float* a_d     = (float*)alloc((size_t)NODES * HEADS * 4);
  float* Ws      = (float*)alloc(FD * HEADS * 4);
  float* Wd      = (float*)alloc(FD * HEADS * 4);
  float* Mtab    = (float*)alloc(NFC * KSZ * VOCS * 4);
  int*   rowst   = (int*)alloc((NODES + 1) * 4);
  float* dinv    = (float*)alloc(NODES * 4);
  int*   bstart  = (int*)alloc((GB + 1) * 4);
  float* xg_pool = (float*)alloc((size_t)GB * HIDD * 4);    // fully written by k_pool
  // ---- contiguous zero-initialized region (single memset) ----
  size_t zoff = off;
  int*   cnt     = (int*)alloc(NODES * 4);
  int*   cur     = (int*)alloc(NODES * 4);
  int*   es_src  = (int*)alloc((size_t)ETOT * 4);
  float* xg1     = (float*)alloc((size_t)GB * 1500 * 4);
  float* xc      = (float*)alloc((size_t)GB * 256 * 4);
  float* xf1     = (float*)alloc((size_t)GB * 1024 * 4);
  float* xf2     = (float*)alloc((size_t)GB * 512 * 4);
  float* xf3     = (float*)alloc((size_t)GB * 256 * 4);
  float* xf4     = (float*)alloc((size_t)GB * 128 * 4);
  int*   diag    = (int*)alloc(2 * 4);
  size_t zlen = off - zoff;

  bf16* x2b = x1p;  // x1p dead after gemm2; reuse (stride HP == KP2)
  bf16*  cT   = (bf16*)aggx;
  size_t cTb  = ((size_t)KFXT * MB2 * 2 + 255) & ~(size_t)255;
  float* part = (float*)((char*)aggx + cTb);

  hipMemsetAsync(w + zoff, 0, zlen, stream);

  k_detect<<<1, 256, 0, stream>>>(x, diag);

  k_tr_gcnw<<<dim3(KP2 / 32, NPADB / 32), 256, 0, stream>>>(gcn_W, gcnWt, diag);
  k_prepg<<<(HEADS * 128 * HK + 255) / 256, 256, 0, stream>>>(gat_W, a_src, a_dst,
                                                              Ws, Wd, gatWt2, diag);
  k_zero_x1pad<<<((MPAD - NODES) * KP2 + NODES * 20 + 255) / 256, 256, 0, stream>>>(x1p);
  k_prep_mtab<<<(NFC * KSZ * VOCS + 255) / 256, 256, 0, stream>>>(emb, cW, Mtab, diag);

  k_asd<<<(NODES + 255) / 256, 256, 0, stream>>>(x, Ws, Wd, a_s, a_d, diag);

  // CSR + metadata
  k_count<<<(ETOT + 255) / 256, 256, 0, stream>>>(ei, cnt, diag);
  k_scan<<<1, 1024, 0, stream>>>(cnt, rowst);
  k_scatter<<<(ETOT + 255) / 256, 256, 0, stream>>>(ei, rowst, cur, es_src, diag);
  k_graphmeta<<<(NODES + 255) / 256, 256, 0, stream>>>(cnt, cur, rowst, batch,
                                                       dinv, bstart, diag);

  // fused softmax + x-space GAT gather, then per-head MFMA GEMM
  k_gatx<<<NODES, 64, 0, stream>>>(es_src, rowst, a_s, a_d, x, aggx, diag);
  k_hgemm<<<dim3(MPAD / MT, HEADS), 256, 0, stream>>>(aggx, gatWt2, gat_b, x1p, diag);

  // h2 = x1 @ gcn_W  (MFMA, stride HP)
  k_gemm_mfma<<<dim3(NPADB / NT, MPAD / MT), 256, 0, stream>>>(
      x1p, KP2, gcnWt, KP2, h_buf, HP, HP, NODES, KP2);

  // interleaved GCN gather -> x2b, then sorted-segment pool
  k_gcng<<<NODES * PNL, 64, 0, stream>>>(es_src, rowst, dinv, h_buf, gcn_b, x2b, diag);
  k_pool<<<GB, 256, 0, stream>>>(x2b, bstart, xg_pool);

  // conv -> K-major cT (aliases aggx), then streaming fxt + reduce
  k_convT<<<dim3((COUT + 31) / 32, NFC), 256, 0, stream>>>(target, Mtab, cb, cT, diag);
  k_fxt<<<dim3(2, FXT_KS), 256, 0, stream>>>(cT, fxt_W, part, diag);
  k_fxt_red<<<GB, 128, 0, stream>>>(part, fxt_b, xc, diag);

  // graph MLP head + fusion MLP via MFMA
  k_mlp_mfma<<<dim3(24, 4), 256, 0, stream>>>(xg_pool, HIDD, fcg1_W, fcg1_b,
                                              xg1, 1500, 0, GB, 1500, HIDD, 4, 0, 0, diag);
  k_mlp_mfma<<<dim3(2, 16), 256, 0, stream>>>(xg1, 1500, fcg2_W, fcg2_b,
                                              xc, 256, 0, GB, 128, 1500, 16, 1, 0, diag);
  k_mlp_mfma<<<dim3(16, 4), 256, 0, stream>>>(xc, 256, f1_W, f1_b,
                                              xf1, 1024, 0, GB, 1024, 256, 4, 0, 0, diag);
  k_mlp_mfma<<<dim3(8, 8), 256, 0, stream>>>(xf1, 1024, f2_W, f2_b,
                                             xf2, 512, 0, GB, 512, 1024, 8, 1, 0, diag);
  k_mlp_mfma<<<dim3(4, 8), 256, 0, stream>>>(xf2, 512, f3_W, f3_b,
                                             xf3, 256, 0, GB, 256, 512, 8, 1, 0, diag);
  k_mlp_mfma<<<dim3(2, 8), 256, 0, stream>>>(xf3, 256, f4_W, f4_b,
                                             xf4, 128, 0, GB, 128, 256, 8, 1, 0, diag);
  k_out<<<GB, 64, 0, stream>>>(xf4, o_W, o_b, d_out, diag);
}